// Round 8
// baseline (2002.732 us; speedup 1.0000x reference)
//
#include <hip/hip_runtime.h>
#include <hip/hip_bf16.h>

#define TD 384
#define NHEAD 6
#define NFF 1536
#define NB 16
#define NTOK 481
#define NROWS (NB*NTOK)   // 7696

typedef __attribute__((ext_vector_type(8))) __bf16 bf16x8;
typedef __attribute__((ext_vector_type(4))) __bf16 bf16x4;
typedef __attribute__((ext_vector_type(4))) float f32x4;

static __device__ __forceinline__ float gelu_f(float v){
    return 0.5f*v*(1.0f + erff(v*0.70710678118654752f));
}

static __device__ __forceinline__ void gload16(const void* g, void* l){
    __builtin_amdgcn_global_load_lds((const __attribute__((address_space(1))) void*)g,
                                     (__attribute__((address_space(3))) void*)l, 16, 0, 0);
}

// stage ROWS x 64 bf16 tile into linear LDS via global_load_lds, XOR-swizzled SOURCE (T2, rule 21).
template<int ROWS>
static __device__ __forceinline__ void stageT(const __bf16* g, int ldel, __bf16* lds, int w, int lane){
    #pragma unroll
    for (int j = 0; j < ROWS/32; ++j){
        int i = w*(ROWS/32) + j;
        int ol = i*1024 + lane*16;
        int row = ol >> 7, colb = ol & 127;
        int sc = colb ^ ((row & 7) << 4);
        gload16((const char*)g + (long)row*ldel*2 + sc, (char*)lds + i*1024);
    }
}

// ---------------- bf16 MFMA GEMM with optional folded-LN epilogue ----------------
// A: (M,K) bf16 lda (rows padded); B: (N,K) bf16 ldb; C fp32/bf16 (obf).
// MR!=null: v = r*(acc - mu*s[col]) + b2[col]  (LN folded into B-weights), else v=acc*scale+bias.
// Tile 64x64, 4 waves (2x2), dbuf LDS, counted vmcnt(4), XCD-chunked swizzle.
__global__ __launch_bounds__(256) void mgemm(
    const __bf16* __restrict__ A, int lda, long sA,
    const __bf16* __restrict__ Bm, int ldb, long sB,
    void* __restrict__ Cp, int ldc, long sC,
    const float* __restrict__ bias,
    const float* __restrict__ Rp, long sR,
    const float2* __restrict__ MR, long sMR, const float2* __restrict__ SB2,
    __bf16* __restrict__ Xbp,
    int M, int N, int K, float scale, int act, int obf)
{
    __shared__ __align__(16) __bf16 As[2][64*64];
    __shared__ __align__(16) __bf16 Bs[2][64*64];
    const int bz = blockIdx.z;
    A  += (long)bz*sA; Bm += (long)bz*sB;

    const int nwg = gridDim.x*gridDim.y;
    const int id  = blockIdx.y*gridDim.x + blockIdx.x;
    const int q8  = nwg >> 3, r8 = nwg & 7;
    const int xcd = id & 7, sub = id >> 3;
    const int nid = (xcd < r8 ? xcd*(q8+1) : r8*(q8+1) + (xcd-r8)*q8) + sub;
    const int m0 = (nid / gridDim.x) * 64, n0 = (nid % gridDim.x) * 64;

    const int tid = threadIdx.x;
    const int w = tid >> 6, lane = tid & 63;
    const int wr = w >> 1, wc = w & 1;
    const int lr = lane & 15, lg = lane >> 4;

    f32x4 acc[2][2];
    #pragma unroll
    for (int m=0;m<2;++m)
        #pragma unroll
        for (int n=0;n<2;++n)
            acc[m][n] = (f32x4){0.f,0.f,0.f,0.f};

    const __bf16* Ag = A + (long)m0*lda;
    const __bf16* Bg = Bm + (long)n0*ldb;
    const int NT = K >> 6;

    stageT<64>(Ag, lda, As[0], w, lane);
    stageT<64>(Bg, ldb, Bs[0], w, lane);
    int cur = 0;
    for (int t = 0; t < NT; ++t){
        if (t+1 < NT){
            stageT<64>(Ag + (t+1)*64, lda, As[cur^1], w, lane);
            stageT<64>(Bg + (t+1)*64, ldb, Bs[cur^1], w, lane);
            asm volatile("s_waitcnt vmcnt(4)" ::: "memory");
        } else {
            asm volatile("s_waitcnt vmcnt(0)" ::: "memory");
        }
        __builtin_amdgcn_sched_barrier(0);
        __builtin_amdgcn_s_barrier();
        #pragma unroll
        for (int kk=0;kk<2;++kk){
            const int sa = ((kk*64 + lg*16) ^ ((lr&7)<<4));
            bf16x8 af[2], bfr[2];
            #pragma unroll
            for (int m=0;m<2;++m)
                af[m] = *(const bf16x8*)((const char*)&As[cur][0] + (wr*32 + m*16 + lr)*128 + sa);
            #pragma unroll
            for (int n=0;n<2;++n)
                bfr[n] = *(const bf16x8*)((const char*)&Bs[cur][0] + (wc*32 + n*16 + lr)*128 + sa);
            #pragma unroll
            for (int m=0;m<2;++m)
                #pragma unroll
                for (int n=0;n<2;++n)
                    acc[m][n] = __builtin_amdgcn_mfma_f32_16x16x32_bf16(af[m], bfr[n], acc[m][n], 0, 0, 0);
        }
        __builtin_amdgcn_s_barrier();
        cur ^= 1;
    }

    #pragma unroll
    for (int m=0;m<2;++m){
        #pragma unroll
        for (int e=0;e<4;++e){
            int row = m0 + wr*32 + m*16 + lg*4 + e;
            if (row >= M) continue;
            float2 mr = MR ? MR[(long)bz*sMR + row] : make_float2(0.f,0.f);
            #pragma unroll
            for (int n=0;n<2;++n){
                int col = n0 + wc*32 + n*16 + lr;
                if (col >= N) continue;
                float v = acc[m][n][e];
                if (MR){
                    float2 sb = SB2[col];
                    v = mr.y*(v - mr.x*sb.x) + sb.y;
                } else {
                    v = v*scale;
                    if (bias) v += bias[col];
                }
                if (act) v = gelu_f(v);
                if (Rp) v += Rp[(long)bz*sR + (long)row*ldc + col];
                if (obf) ((__bf16*)Cp)[(long)bz*sC + (long)row*ldc + col] = (__bf16)v;
                else     ((float*)Cp)[(long)bz*sC + (long)row*ldc + col] = v;
                if (Xbp) Xbp[(long)row*ldc + col] = (__bf16)v;
            }
        }
    }
}

// ---------------- MFMA flash attention, pipelined (K dbuf gload_lds, V reg-prefetch) ----------------
__global__ __launch_bounds__(256) void attn2(const __bf16* __restrict__ QKV, __bf16* __restrict__ O)
{
    __shared__ __align__(16) __bf16 Ks[2][64*64];
    __shared__ __align__(16) __bf16 VT[64*72];
    __shared__ __align__(16) __bf16 Ps[64*72];
    const int qt=blockIdx.x, h=blockIdx.y, b=blockIdx.z;
    const int tid=threadIdx.x, w=tid>>6, lane=tid&63;
    const int lr=lane&15, lg=lane>>4;
    const int kv0 = tid & 63, d80 = tid >> 6;   // V staging coords (kv fixed per thread)
    const __bf16* base = QKV + (long)b*NTOK*1152;
    const long qrow = qt*64 + w*16 + lr;
    const bf16x8 qa0 = *(const bf16x8*)(base + qrow*1152 + h*64 + lg*8);
    const bf16x8 qa1 = *(const bf16x8*)(base + qrow*1152 + h*64 + 32 + lg*8);

    // prologue: stage K tile0 (LDS) + V tile0 (regs)
    #pragma unroll
    for (int j=0;j<2;++j){
        int i = w*2+j;
        int ol = i*1024 + lane*16;
        int row = ol>>7, colb = ol&127;
        int sc = colb ^ ((row&7)<<4);
        gload16((const char*)base + ((long)row*1152 + 384 + h*64)*2 + sc, (char*)Ks[0] + i*1024);
    }
    bf16x8 vv0 = *(const bf16x8*)(base + (long)kv0*1152 + 768 + h*64 + d80*8);
    bf16x8 vv1 = *(const bf16x8*)(base + (long)kv0*1152 + 768 + h*64 + (d80+4)*8);

    f32x4 oacc[4];
    float mo[4], lo[4];
    #pragma unroll
    for (int e=0;e<4;++e){ mo[e]=-1e30f; lo[e]=0.f; }
    #pragma unroll
    for (int n=0;n<4;++n) oacc[n]=(f32x4){0.f,0.f,0.f,0.f};

    int cur = 0;
    for (int kt=0; kt<8; ++kt){
        // K[kt] (lds) and V[kt] (regs) landed: both issued last iteration, latency covered by compute
        asm volatile("s_waitcnt vmcnt(0)" ::: "memory");
        __builtin_amdgcn_sched_barrier(0);
        #pragma unroll
        for (int jj=0;jj<8;++jj) VT[(d80*8+jj)*72 + kv0] = vv0[jj];
        #pragma unroll
        for (int jj=0;jj<8;++jj) VT[((d80+4)*8+jj)*72 + kv0] = vv1[jj];
        if (kt+1 < 8){
            #pragma unroll
            for (int j=0;j<2;++j){            // K[kt+1] -> other LDS buffer (readers done at last barrier)
                int i = w*2+j;
                int ol = i*1024 + lane*16;
                int row = ol>>7, colb = ol&127;
                int sc = colb ^ ((row&7)<<4);
                gload16((const char*)base + ((long)((kt+1)*64+row)*1152 + 384 + h*64)*2 + sc,
                        (char*)Ks[cur^1] + i*1024);
            }
            vv0 = *(const bf16x8*)(base + (long)((kt+1)*64+kv0)*1152 + 768 + h*64 + d80*8);
            vv1 = *(const bf16x8*)(base + (long)((kt+1)*64+kv0)*1152 + 768 + h*64 + (d80+4)*8);
        }
        asm volatile("s_waitcnt lgkmcnt(0)" ::: "memory");   // my VT writes done
        __builtin_amdgcn_sched_barrier(0);
        __builtin_amdgcn_s_barrier();                        // VT + all waves' K[kt] visible

        f32x4 s[4];
        #pragma unroll
        for (int n=0;n<4;++n) s[n]=(f32x4){0.f,0.f,0.f,0.f};
        #pragma unroll
        for (int kk=0;kk<2;++kk){
            const int sa = ((kk*64 + lg*16) ^ ((lr&7)<<4));
            #pragma unroll
            for (int n=0;n<4;++n){
                bf16x8 kb = *(const bf16x8*)((const char*)&Ks[cur][0] + (n*16+lr)*128 + sa);
                s[n] = __builtin_amdgcn_mfma_f32_16x16x32_bf16(kk? qa1:qa0, kb, s[n], 0,0,0);
            }
        }
        #pragma unroll
        for (int n=0;n<4;++n){
            int col = kt*64 + n*16 + lr;
            bool bad = col >= NTOK;
            #pragma unroll
            for (int e=0;e<4;++e) s[n][e] = bad ? -1e30f : s[n][e]*0.125f;
        }
        #pragma unroll
        for (int e=0;e<4;++e){
            float rm = fmaxf(fmaxf(s[0][e],s[1][e]), fmaxf(s[2][e],s[3][e]));
            rm = fmaxf(rm, __shfl_xor(rm,1));
            rm = fmaxf(rm, __shfl_xor(rm,2));
            rm = fmaxf(rm, __shfl_xor(rm,4));
            rm = fmaxf(rm, __shfl_xor(rm,8));
            float mn = fmaxf(mo[e], rm);
            float al = __expf(mo[e]-mn);
            float rs = 0.f;
            #pragma unroll
            for (int n=0;n<4;++n){ float p=__expf(s[n][e]-mn); s[n][e]=p; rs+=p; }
            rs += __shfl_xor(rs,1); rs += __shfl_xor(rs,2);
            rs += __shfl_xor(rs,4); rs += __shfl_xor(rs,8);
            lo[e] = lo[e]*al + rs; mo[e]=mn;
            #pragma unroll
            for (int n=0;n<4;++n) oacc[n][e] *= al;
        }
        #pragma unroll
        for (int n=0;n<4;++n)
            #pragma unroll
            for (int e=0;e<4;++e)
                Ps[(w*16+lg*4+e)*72 + n*16+lr] = (__bf16)s[n][e];
        #pragma unroll
        for (int kk=0;kk<2;++kk){
            bf16x8 pa = *(const bf16x8*)&Ps[(w*16+lr)*72 + kk*32 + lg*8];
            #pragma unroll
            for (int n=0;n<4;++n){
                bf16x8 vf = *(const bf16x8*)&VT[(n*16+lr)*72 + kk*32 + lg*8];
                oacc[n] = __builtin_amdgcn_mfma_f32_16x16x32_bf16(pa, vf, oacc[n], 0,0,0);
            }
        }
        __builtin_amdgcn_s_barrier();   // all PV reads of VT / QK reads of Ks[cur] done
        cur ^= 1;
    }
    #pragma unroll
    for (int e=0;e<4;++e){
        int q = qt*64 + w*16 + lg*4 + e;
        if (q < NTOK){
            float inv = 1.f/lo[e];
            __bf16* op = O + ((long)b*NTOK + q)*TD + h*64;
            #pragma unroll
            for (int n=0;n<4;++n)
                op[n*16+lr] = (__bf16)(oacc[n][e]*inv);
        }
    }
}

// ---------------- per-row mean/rstd of bf16 matrix (LN stats) ----------------
__global__ __launch_bounds__(256) void stats_kernel(const __bf16* __restrict__ Xb, float2* __restrict__ MR, int nrows)
{
    int row = blockIdx.x*4 + (threadIdx.x>>6);
    if (row >= nrows) return;
    int lane = threadIdx.x & 63;
    const uint* p = (const uint*)(Xb + (long)row*384) + lane*3;
    float s=0.f, q=0.f;
    #pragma unroll
    for (int i=0;i<3;++i){
        uint u = p[i];
        float a = __uint_as_float(u<<16);
        float b = __uint_as_float(u & 0xFFFF0000u);
        s += a+b; q += a*a + b*b;
    }
    #pragma unroll
    for (int d=1; d<64; d<<=1){ s += __shfl_xor(s,d); q += __shfl_xor(q,d); }
    if (lane==0){
        float mu = s*(1.f/384.f);
        float var = q*(1.f/384.f) - mu*mu;
        MR[row] = make_float2(mu, rsqrtf(var + 1e-6f));
    }
}

// ---------------- fold LN scale into weights: d = bf16(lnw[k] * W) ----------------
__global__ void wfold_kernel(const float* __restrict__ s, const float* __restrict__ lnw,
                             __bf16* __restrict__ d, int n4, int per_layer4)
{
    int i = blockIdx.x*256 + threadIdx.x;
    if (i >= n4) return;
    int layer = i / per_layer4;
    int k = (i*4) % 384;
    float4 v = ((const float4*)s)[i];
    const float4 lw = *(const float4*)(lnw + layer*384 + k);
    bf16x4 p; p[0]=(__bf16)(v.x*lw.x); p[1]=(__bf16)(v.y*lw.y); p[2]=(__bf16)(v.z*lw.z); p[3]=(__bf16)(v.w*lw.w);
    ((bf16x4*)d)[i] = p;
}

// ---------------- per-row s[n]=sum lnw*W, b2[n]=bias+sum lnb*W ----------------
__global__ __launch_bounds__(256) void rowsum_kernel(const float* __restrict__ W,
    const float* __restrict__ lnw, const float* __restrict__ lnb, const float* __restrict__ bias,
    float2* __restrict__ SB2, int nrows, int rows_per_layer)
{
    int row = blockIdx.x*4 + (threadIdx.x>>6);
    if (row >= nrows) return;
    int lane = threadIdx.x & 63;
    int layer = row / rows_per_layer;
    const float* wr = W + (long)row*384;
    const float* lw = lnw + layer*384;
    const float* lb = lnb + layer*384;
    float s=0.f, t=0.f;
    #pragma unroll
    for (int i=0;i<6;++i){
        int k = lane + i*64;
        float wv = wr[k];
        s += lw[k]*wv; t += lb[k]*wv;
    }
    #pragma unroll
    for (int d=1; d<64; d<<=1){ s += __shfl_xor(s,d); t += __shfl_xor(t,d); }
    if (lane==0) SB2[row] = make_float2(s, bias ? t + bias[row] : t);
}

// ---------------- weight fp32 -> bf16 ----------------
__global__ void wconv_kernel(const float* __restrict__ s, __bf16* __restrict__ d, int n4){
    int i = blockIdx.x*256 + threadIdx.x;
    if (i < n4){
        float4 v = ((const float4*)s)[i];
        bf16x4 p; p[0]=(__bf16)v.x; p[1]=(__bf16)v.y; p[2]=(__bf16)v.z; p[3]=(__bf16)v.w;
        ((bf16x4*)d)[i] = p;
    }
}

// ---------------- im2col (bf16 out) ----------------
__global__ void im2col_kernel(const float* __restrict__ in, __bf16* __restrict__ outp)
{
    long idx = (long)blockIdx.x*256 + threadIdx.x;
    if (idx >= (long)7680*1792) return;
    int k = (int)(idx % 1792);
    long m = idx / 1792;
    int pw = (int)(m % 40);
    long t2 = m / 40;
    int ph = (int)(t2 % 12);
    int b  = (int)(t2 / 12);
    int kw = k & 15, kh = (k >> 4) & 15, c = k >> 8;
    outp[idx] = (__bf16)in[(((long)(b*7 + c)*192) + ph*16 + kh)*640 + pw*16 + kw];
}

// ---------------- assemble x = [cls; conv_out] + pos (fp32 X + bf16 Xb) ----------------
__global__ void assemble_kernel(const float* __restrict__ CO, const float* __restrict__ cls,
    const float* __restrict__ pos, float* __restrict__ X, __bf16* __restrict__ Xb)
{
    long idx = (long)blockIdx.x*256 + threadIdx.x;
    if (idx >= (long)NROWS*TD) return;
    int d = (int)(idx % TD);
    long r = idx / TD;
    int tok = (int)(r % NTOK);
    int b   = (int)(r / NTOK);
    float v = (tok == 0) ? cls[d] : CO[((long)b*480 + tok-1)*TD + d];
    v += pos[tok*TD + d];
    X[idx] = v;
    Xb[idx] = (__bf16)v;
}

// ---------------- pose maps ----------------
__global__ __launch_bounds__(256) void pose_maps_kernel(const float* __restrict__ PA,
    float* __restrict__ attn_map, float* __restrict__ masked_map)
{
    int i = blockIdx.x;   // 0..39
    int b = blockIdx.y;   // 0..15
    int t = threadIdx.x;
    float accA[12], accM[12];
    #pragma unroll
    for (int j=0;j<12;++j){ accA[j]=0.f; accM[j]=0.f; }
    for (int a = t; a < 480; a += 256) {
        const float* row = PA + ((long)(b*480 + a))*480 + i;
        float v[12];
        float mx = -1e30f;
        #pragma unroll
        for (int j=0;j<12;++j){ v[j] = row[40*j]; mx = fmaxf(mx, v[j]); }
        float sum = 0.f;
        #pragma unroll
        for (int j=0;j<12;++j){ v[j] = expf(v[j]-mx); sum += v[j]; }
        float invs = 1.f/sum;
        #pragma unroll
        for (int j=0;j<12;++j) v[j] *= invs;
        float srt[12];
        #pragma unroll
        for (int j=0;j<12;++j){
            float x = v[j]; int p = j;
            while (p > 0 && srt[p-1] > x){ srt[p]=srt[p-1]; --p; }
            srt[p]=x;
        }
        float med = srt[5];
        #pragma unroll
        for (int j=0;j<12;++j){
            accA[j] += v[j];
            accM[j] += (v[j] > med) ? 0.f : v[j];
        }
    }
    __shared__ float redA[256*12];
    __shared__ float redM[256*12];
    #pragma unroll
    for (int j=0;j<12;++j){ redA[t*12+j]=accA[j]; redM[t*12+j]=accM[j]; }
    __syncthreads();
    for (int sgap=128; sgap>0; sgap>>=1){
        if (t < sgap){
            #pragma unroll
            for (int j=0;j<12;++j){
                redA[t*12+j] += redA[(t+sgap)*12+j];
                redM[t*12+j] += redM[(t+sgap)*12+j];
            }
        }
        __syncthreads();
    }
    if (t < 12){
        attn_map  [(b*12 + t)*40 + i] = redA[t] * (1.f/480.f);
        masked_map[(b*12 + t)*40 + i] = redM[t] * (1.f/480.f) * (1.f/24.f);
    }
}

// ---------------- column-sum of pose V (bf16 in), 4-way row-split ----------------
__global__ __launch_bounds__(384) void colsum4_kernel(const __bf16* __restrict__ QKV2, float* __restrict__ CS4)
{
    int b = blockIdx.x, j = blockIdx.y, c = threadIdx.x;
    const __bf16* p = QKV2 + (long)b*480*1152 + 768 + c;
    float s = 0.f;
    for (int a = j*120; a < j*120+120; ++a) s += (float)p[(long)a*1152];
    CS4[((long)b*4 + j)*384 + c] = s;
}

// ---------------- final pose output: LN(40*colsum @ pose_w^T + pose_b) ----------------
__global__ __launch_bounds__(384) void pose_final_kernel(const float* __restrict__ CS4,
    const float* __restrict__ PW, const float* __restrict__ PB,
    const float* __restrict__ NW, const float* __restrict__ NBb, float* __restrict__ out)
{
    int b = blockIdx.x, c = threadIdx.x;
    const float* s0 = CS4 + (long)b*1536;
    __shared__ float sv[384];
    sv[c] = s0[c] + s0[384+c] + s0[768+c] + s0[1152+c];
    __syncthreads();
    const float* wr = PW + (long)c*384;
    float acc = 0.f;
    for (int k = 0; k < 384; ++k) acc += sv[k]*wr[k];
    acc = 40.f*acc + PB[c];
    float s = acc, q = acc*acc;
    #pragma unroll
    for (int w=1; w<64; w<<=1){ s += __shfl_xor(s,w); q += __shfl_xor(q,w); }
    __shared__ float sm[6][2];
    if ((c & 63) == 0){ sm[c>>6][0]=s; sm[c>>6][1]=q; }
    __syncthreads();
    float S=0.f, Q=0.f;
    for (int i=0;i<6;++i){ S+=sm[i][0]; Q+=sm[i][1]; }
    float mean = S*(1.f/384.f);
    float var  = Q*(1.f/384.f) - mean*mean;
    float rstd = rsqrtf(var + 1e-6f);
    out[b*384 + c] = (acc-mean)*rstd*NW[c] + NBb[c];
}

extern "C" void kernel_launch(void* const* d_in, const int* in_sizes, int n_in,
                              void* d_out, int out_size, void* d_ws, size_t ws_size,
                              hipStream_t stream)
{
    const float* input  = (const float*)d_in[0];
    const float* conv_w = (const float*)d_in[1];
    const float* conv_b = (const float*)d_in[2];
    const float* cls    = (const float*)d_in[3];
    const float* pos    = (const float*)d_in[4];
    const float* ln1w   = (const float*)d_in[5];
    const float* ln1b   = (const float*)d_in[6];
    const float* qkvw   = (const float*)d_in[7];
    const float* qkvb   = (const float*)d_in[8];
    const float* projw  = (const float*)d_in[9];
    const float* projb  = (const float*)d_in[10];
    const float* ln2w   = (const float*)d_in[11];
    const float* ln2b   = (const float*)d_in[12];
    const float* fc1w   = (const float*)d_in[13];
    const float* fc1b   = (const float*)d_in[14];
    const float* fc2w   = (const float*)d_in[15];
    const float* fc2b   = (const float*)d_in[16];
    const float* normw  = (const float*)d_in[17];
    const float* normb  = (const float*)d_in[18];
    const float* toqkvw = (const float*)d_in[19];
    const float* posew  = (const float*)d_in[20];
    const float* poseb  = (const float*)d_in[21];
    float* out = (float*)d_out;
    float* ws  = (float*)d_ws;

    // ---- workspace layout (float offsets); activation rows padded to 7808 ----
    __bf16* WB    = (__bf16*)ws;                   // bf16 weights, 22,364,160 bf16
    float*  X     = ws + 11182080;                 // 7696*384 fp32 residual
    __bf16* Xb    = (__bf16*)(ws + 14137344);      // 7808*384 bf16 mirror of X
    __bf16* QKVb  = (__bf16*)(ws + 15636480);      // 7808*1536 bf16
    __bf16* Obuf  = (__bf16*)(ws + 21633024);      // 7808*384 bf16
    float*  PAb   = ws + 23132160;                 // 16*480*480 fp32 (also conv tmp)
    float*  CS4   = PAb + 3686400;                 // 24576 f
    float2* MR    = (float2*)(ws + 26843136);      // 7808 float2
    float2* SB2q  = (float2*)(ws + 26858752);      // 13824 float2
    float2* SB2f  = (float2*)(ws + 26886400);      // 18432 float2
    float2* SB2t  = (float2*)(ws + 26923264);      // 1152 float2
    __bf16* IM2C  = QKVb;                          // alias (pre-layer only)

    __bf16* Wconv = WB;
    __bf16* Wqkv  = WB + 688128;    // folded: ln1w * qkvw
    __bf16* Wproj = WB + 5996544;
    __bf16* Wfc1  = WB + 7766016;   // folded: ln2w * fc1w
    __bf16* Wfc2  = WB + 14843904;
    __bf16* Wtoq  = WB + 21921792;  // folded: normw * toqkvw

    // ---- weight precompute ----
    wconv_kernel<<<dim3((172032+255)/256), 256, 0, stream>>>(conv_w, Wconv, 172032);
    wconv_kernel<<<dim3((442368+255)/256), 256, 0, stream>>>(projw, Wproj, 442368);
    wconv_kernel<<<dim3((1769472+255)/256), 256, 0, stream>>>(fc2w,  Wfc2, 1769472);
    wfold_kernel<<<dim3((1327104+255)/256), 256, 0, stream>>>(qkvw, ln1w, Wqkv, 1327104, 110592);
    wfold_kernel<<<dim3((1769472+255)/256), 256, 0, stream>>>(fc1w, ln2w, Wfc1, 1769472, 147456);
    wfold_kernel<<<dim3((110592+255)/256), 256, 0, stream>>>(toqkvw, normw, Wtoq, 110592, 110592);
    rowsum_kernel<<<dim3(13824/4), 256, 0, stream>>>(qkvw, ln1w, ln1b, qkvb, SB2q, 13824, 1152);
    rowsum_kernel<<<dim3(18432/4), 256, 0, stream>>>(fc1w, ln2w, ln2b, fc1b, SB2f, 18432, 1536);
    rowsum_kernel<<<dim3(1152/4), 256, 0, stream>>>(toqkvw, normw, normb, nullptr, SB2t, 1152, 1152);

    // ---- patch embed ----
    {
        long total = (long)7680*1792;
        im2col_kernel<<<dim3((unsigned)((total+255)/256)), 256, 0, stream>>>(input, IM2C);
    }
    mgemm<<<dim3(6, 120, 1), 256, 0, stream>>>(IM2C, 1792, 0, Wconv, 1792, 0,
        PAb, 384, 0, conv_b, nullptr, 0, nullptr, 0, nullptr, nullptr, 7680, 384, 1792, 1.f, 0, 0);
    assemble_kernel<<<dim3((NROWS*TD+255)/256), 256, 0, stream>>>(PAb, cls, pos, X, Xb);

    // ---- transformer layers (LN folded into qkv/fc1 weights) ----
    for (int i = 0; i < 12; ++i) {
        stats_kernel<<<dim3((NROWS+3)/4), 256, 0, stream>>>(Xb, MR, NROWS);
        mgemm<<<dim3(18, 121, 1), 256, 0, stream>>>(Xb, 384, 0, Wqkv + (long)i*1152*384, 384, 0,
            QKVb, 1152, 0, nullptr, nullptr, 0, MR, 0, SB2q + (long)i*1152, nullptr,
            NROWS, 1152, 384, 1.f, 0, 1);
        attn2<<<dim3(8, NHEAD, NB), 256, 0, stream>>>(QKVb, Obuf);
        mgemm<<<dim3(6, 121, 1), 256, 0, stream>>>(Obuf, 384, 0, Wproj + (long)i*384*384, 384, 0,
            X, 384, 0, projb + i*384, X, 0, nullptr, 0, nullptr, Xb,
            NROWS, 384, 384, 1.f, 0, 0);
        stats_kernel<<<dim3((NROWS+3)/4), 256, 0, stream>>>(Xb, MR, NROWS);
        mgemm<<<dim3(24, 121, 1), 256, 0, stream>>>(Xb, 384, 0, Wfc1 + (long)i*1536*384, 384, 0,
            QKVb, 1536, 0, nullptr, nullptr, 0, MR, 0, SB2f + (long)i*1536, nullptr,
            NROWS, 1536, 384, 1.f, 1, 1);
        mgemm<<<dim3(6, 121, 1), 256, 0, stream>>>(QKVb, 1536, 0, Wfc2 + (long)i*384*1536, 1536, 0,
            X, 384, 0, fc2b + i*384, X, 0, nullptr, 0, nullptr, Xb,
            NROWS, 384, 1536, 1.f, 0, 0);
    }

    // ---- pose head (final norm folded into toqkv) ----
    stats_kernel<<<dim3((NROWS+3)/4), 256, 0, stream>>>(Xb, MR, NROWS);
    mgemm<<<dim3(18, 8, 16), 256, 0, stream>>>(Xb + 384, 384, (long)481*384,
        Wtoq, 384, 0, QKVb, 1152, (long)480*1152, nullptr, nullptr, 0,
        MR + 1, 481, SB2t, nullptr, 480, 1152, 384, 1.f, 0, 1);
    mgemm<<<dim3(8, 8, 16), 256, 0, stream>>>(QKVb, 1152, (long)480*1152,
        QKVb + 384, 1152, (long)480*1152, PAb, 480, (long)480*480, nullptr, nullptr, 0,
        nullptr, 0, nullptr, nullptr, 480, 480, 384, 0.05103f*0.01f, 0, 0);
    pose_maps_kernel<<<dim3(40, 16), 256, 0, stream>>>(PAb, out + 6144, out + 13824);
    colsum4_kernel<<<dim3(16, 4), 384, 0, stream>>>(QKVb, CS4);
    pose_final_kernel<<<dim3(16), 384, 0, stream>>>(CS4, posew, poseb, normw, normb, out);
}